// Round 9
// baseline (30.462 us; speedup 1.0000x reference)
//
#include <hip/hip_runtime.h>
#include <stdint.h>

// Problem: x (4096,2048) int32 {0,1}; references (1024,2048) f32 {0,1};
// out (4096,1024) f32 = (hamming - 1024) / (0.5*sqrt(2048)).
// Identity: with s=1-2x, t=1-2r in {+-1}, hamming = (2048 - s.t)/2, so
//   out[b,d] = -(inv_std/2) * dot_pm1(b,d)     (exact integer dot)
constexpr int B_ROWS = 4096;
constexpr int D_ROWS = 1024;
constexpr int L_LEN  = 2048;

using int32x4 = __attribute__((ext_vector_type(4))) int;

// ---------------------------------------------------------------------------
// Kernel 1 (UNCHANGED from R7 — control): convert both inputs to +-1 int8
// (0 -> 0x01, 1 -> 0xFF). Reads 16 B/lane coalesced, writes 4 B/lane.
// ---------------------------------------------------------------------------
__global__ __launch_bounds__(256) void convert_kernel(
    const int* __restrict__ x, const float* __restrict__ r,
    uint32_t* __restrict__ xq, uint32_t* __restrict__ rq,
    int groups_x, int groups_total)
{
  const int tid = blockIdx.x * blockDim.x + threadIdx.x;
  const int nth = gridDim.x * blockDim.x;
  for (int g = tid; g < groups_total; g += nth) {
    if (g < groups_x) {
      const int4 v = *reinterpret_cast<const int4*>(x + (size_t)g * 4);
      const uint32_t b0 = v.x ? 0xFFu : 0x01u;
      const uint32_t b1 = v.y ? 0xFFu : 0x01u;
      const uint32_t b2 = v.z ? 0xFFu : 0x01u;
      const uint32_t b3 = v.w ? 0xFFu : 0x01u;
      xq[g] = b0 | (b1 << 8) | (b2 << 16) | (b3 << 24);
    } else {
      const int gr = g - groups_x;
      const float4 v = *reinterpret_cast<const float4*>(r + (size_t)gr * 4);
      const uint32_t b0 = (v.x != 0.0f) ? 0xFFu : 0x01u;
      const uint32_t b1 = (v.y != 0.0f) ? 0xFFu : 0x01u;
      const uint32_t b2 = (v.z != 0.0f) ? 0xFFu : 0x01u;
      const uint32_t b3 = (v.w != 0.0f) ? 0xFFu : 0x01u;
      rq[gr] = b0 | (b1 << 8) | (b2 << 16) | (b3 << 24);
    }
  }
}

// ---------------------------------------------------------------------------
// Kernel 2 v2: i8 GEMM, T3/T4 "minimum 2-phase" double-buffered pipeline.
// Same geometry as R7 (BM=128 BN=64 BK=128, 4 waves 2x2, 16x16x64 MFMA,
// XOR-swizzle rule #21), but now:
//   prologue: STAGE(buf0, tile 0); barrier
//   step t:   STAGE(buf[t+1 & 1], tile t+1)   <- loads in flight during MFMA
//             ds_read buf[t&1] -> 16 MFMA
//             ONE __syncthreads() (vmcnt+lgkm drain, mostly already landed)
// Safety: reads of buf[cur] finish (lgkmcnt before MFMA) before the end-of-
// step barrier; buf[cur] is only overwritten in the NEXT iteration after it.
// LDS 2 x 24 KB = 48 KB. Barrier drains per step: 2 -> 1; load latency
// hidden under ~300 cyc of ds_read+MFMA.
// ---------------------------------------------------------------------------
constexpr int BM = 128;
constexpr int BN = 64;
constexpr int BK = 128;
constexpr int KSTEPS = L_LEN / BK;   // 16

typedef __attribute__((address_space(3))) void       as3_void;
typedef const __attribute__((address_space(1))) void as1_cvoid;

__device__ __forceinline__ void gload_lds16(const void* g, void* l) {
  __builtin_amdgcn_global_load_lds((as1_cvoid*)g, (as3_void*)l, 16, 0, 0);
}

__global__ __launch_bounds__(256) void gemm_i8_kernel(
    const char* __restrict__ Aq, const char* __restrict__ Bq,
    float* __restrict__ out)
{
  __shared__ __align__(16) char A_lds[2][BM * BK];   // 2 x 16 KB
  __shared__ __align__(16) char B_lds[2][BN * BK];   // 2 x  8 KB

  const int t    = threadIdx.x;
  const int lane = t & 63;
  const int w    = t >> 6;          // wave 0..3
  const int wr   = w >> 1;          // wave row (m)
  const int wc   = w & 1;           // wave col (n)
  const int bm   = blockIdx.x * BM;
  const int bn   = blockIdx.y * BN;

  const int l8  = lane >> 3;        // row within 8-row staging group
  const int c16 = lane & 7;         // 16B slot within 128B row

  // Per-lane pre-swizzled global source pointers (rule #21: linear LDS dest,
  // inverse-swizzled source, swizzled read). Row-dependent part is constant
  // across K-steps; only k0 advances.
  const char* gA[4];
#pragma unroll
  for (int c = 0; c < 4; ++c) {
    const int r = c * 32 + w * 8 + l8;
    gA[c] = Aq + (size_t)(bm + r) * L_LEN + ((c16 ^ (r & 7)) * 16);
  }
  const char* gB[2];
#pragma unroll
  for (int c = 0; c < 2; ++c) {
    const int r = c * 32 + w * 8 + l8;
    gB[c] = Bq + (size_t)(bn + r) * L_LEN + ((c16 ^ (r & 7)) * 16);
  }

#define STAGE(buf, k0) do {                                                   \
    _Pragma("unroll") for (int _c = 0; _c < 4; ++_c)                          \
      gload_lds16(gA[_c] + (k0), A_lds[buf] + (_c * 32 + w * 8) * BK);        \
    _Pragma("unroll") for (int _c = 0; _c < 2; ++_c)                          \
      gload_lds16(gB[_c] + (k0), B_lds[buf] + (_c * 32 + w * 8) * BK);        \
  } while (0)

  int32x4 acc[4][2] = {};           // 32 VGPR accumulator, static-indexed

  STAGE(0, 0);
  __syncthreads();

  for (int ks = 0; ks < KSTEPS; ++ks) {
    const int cur = ks & 1;
    if (ks + 1 < KSTEPS) STAGE(cur ^ 1, (ks + 1) * BK);   // prefetch in flight

    // Fragment reads (swizzled) + MFMA from buf[cur].
    int32x4 a[4][2], b[2][2];
#pragma unroll
    for (int kk = 0; kk < 2; ++kk) {
      const int kcol = kk * 64 + (lane >> 4) * 16;
#pragma unroll
      for (int f = 0; f < 4; ++f) {
        const int row = wr * 64 + f * 16 + (lane & 15);
        a[f][kk] = *reinterpret_cast<const int32x4*>(
            A_lds[cur] + row * BK + (kcol ^ ((row & 7) << 4)));
      }
#pragma unroll
      for (int gg = 0; gg < 2; ++gg) {
        const int row = wc * 32 + gg * 16 + (lane & 15);
        b[gg][kk] = *reinterpret_cast<const int32x4*>(
            B_lds[cur] + row * BK + (kcol ^ ((row & 7) << 4)));
      }
    }
#pragma unroll
    for (int f = 0; f < 4; ++f)
#pragma unroll
      for (int gg = 0; gg < 2; ++gg)
#pragma unroll
        for (int kk = 0; kk < 2; ++kk)
          acc[f][gg] = __builtin_amdgcn_mfma_i32_16x16x64_i8(
              a[f][kk], b[gg][kk], acc[f][gg], 0, 0, 0);

    __syncthreads();   // single per-step drain: next tile staged, LDS safe
  }
#undef STAGE

  // Epilogue: C/D layout (verified, dtype-independent): col = lane&15,
  // row = (lane>>4)*4 + reg.  out = dot * (-inv_std/2).
  const float scale = -0.5f * 0.04419417382415922f;
#pragma unroll
  for (int f = 0; f < 4; ++f) {
    const int brow = bm + wr * 64 + f * 16 + (lane >> 4) * 4;
#pragma unroll
    for (int gg = 0; gg < 2; ++gg) {
      const int d = bn + wc * 32 + gg * 16 + (lane & 15);
#pragma unroll
      for (int reg = 0; reg < 4; ++reg)
        out[(size_t)(brow + reg) * D_ROWS + d] = (float)acc[f][gg][reg] * scale;
    }
  }
}

extern "C" void kernel_launch(void* const* d_in, const int* in_sizes, int n_in,
                              void* d_out, int out_size, void* d_ws, size_t ws_size,
                              hipStream_t stream) {
  const int*   x = (const int*)d_in[0];     // (4096, 2048) int32
  const float* r = (const float*)d_in[1];   // (1024, 2048) float32
  float*     out = (float*)d_out;           // (4096, 1024) float32

  char* Aq = (char*)d_ws;                               // 8 MiB  (4096x2048 i8)
  char* Bq = Aq + (size_t)B_ROWS * L_LEN;               // 2 MiB  (1024x2048 i8)

  const int groups_x = B_ROWS * L_LEN / 4;              // 2097152
  const int groups_r = D_ROWS * L_LEN / 4;              // 524288
  const int groups_total = groups_x + groups_r;

  convert_kernel<<<2048, 256, 0, stream>>>(
      x, r, (uint32_t*)Aq, (uint32_t*)Bq, groups_x, groups_total);

  dim3 grid(B_ROWS / BM, D_ROWS / BN);  // (32, 16) = 512 blocks, 2/CU
  gemm_i8_kernel<<<grid, 256, 0, stream>>>(Aq, Bq, out);
}